// Round 9
// baseline (180.591 us; speedup 1.0000x reference)
//
#include <hip/hip_runtime.h>
#include <hip/hip_bf16.h>

typedef float f32x4 __attribute__((ext_vector_type(4)));
typedef float f32x16 __attribute__((ext_vector_type(16)));
typedef int   i32x4  __attribute__((ext_vector_type(4)));
typedef int   i32x8  __attribute__((ext_vector_type(8)));

#define FP8_MAX_F 448.0f
#define SCL1 0x7F7F7F7Fu   /* e8m0 exponent 127 -> scale 1.0, all 4 bytes */

__device__ __forceinline__ float wave_max(float m) {
#pragma unroll
    for (int off = 32; off > 0; off >>= 1)
        m = fmaxf(m, __shfl_xor(m, off));
    return m;
}

// ---------------- stage 1: per-block abs-max partials (no atomics) ----------------
__global__ void amax2_kernel(const float* __restrict__ x, long nx,
                             const float* __restrict__ w, long nw,
                             float* __restrict__ px, float* __restrict__ pw,
                             int ga) {
    __shared__ float red[4];
    const float* src; long n; float* dst; int bid, blocks;
    if ((int)blockIdx.x < ga) { src = x; n = nx; dst = px; bid = blockIdx.x; blocks = ga; }
    else { src = w; n = nw; dst = pw; bid = blockIdx.x - ga; blocks = gridDim.x - ga; }

    const long stride = (long)blocks * blockDim.x * 16;
    long i = ((long)bid * blockDim.x + threadIdx.x) * 16;
    float m = 0.0f;
    for (; i < n; i += stride) {
        f32x4 v0 = *(const f32x4*)(src + i);
        f32x4 v1 = *(const f32x4*)(src + i + 4);
        f32x4 v2 = *(const f32x4*)(src + i + 8);
        f32x4 v3 = *(const f32x4*)(src + i + 12);
        float m0 = fmaxf(fmaxf(fabsf(v0.x), fabsf(v0.y)), fmaxf(fabsf(v0.z), fabsf(v0.w)));
        float m1 = fmaxf(fmaxf(fabsf(v1.x), fabsf(v1.y)), fmaxf(fabsf(v1.z), fabsf(v1.w)));
        float m2 = fmaxf(fmaxf(fabsf(v2.x), fabsf(v2.y)), fmaxf(fabsf(v2.z), fabsf(v2.w)));
        float m3 = fmaxf(fmaxf(fabsf(v3.x), fabsf(v3.y)), fmaxf(fabsf(v3.z), fabsf(v3.w)));
        m = fmaxf(m, fmaxf(fmaxf(m0, m1), fmaxf(m2, m3)));
    }
    m = wave_max(m);
    const int wave = threadIdx.x >> 6;
    if ((threadIdx.x & 63) == 0) red[wave] = m;
    __syncthreads();
    if (threadIdx.x == 0)
        dst[bid] = fmaxf(fmaxf(red[0], red[1]), fmaxf(red[2], red[3]));
}

// ---------------- stage 2: reduce partials -> amax bits (block 0 = x, block 1 = w) ----------------
__global__ void amax_final_kernel(const float* __restrict__ px, int npx,
                                  const float* __restrict__ pw, int npw,
                                  unsigned* __restrict__ amax) {
    __shared__ float red[4];
    const float* p; int n;
    if (blockIdx.x == 0) { p = px; n = npx; } else { p = pw; n = npw; }
    float m = 0.0f;
    for (int i = threadIdx.x; i < n; i += blockDim.x) m = fmaxf(m, p[i]);
    m = wave_max(m);
    const int wave = threadIdx.x >> 6;
    if ((threadIdx.x & 63) == 0) red[wave] = m;
    __syncthreads();
    if (threadIdx.x == 0) {
        m = fmaxf(fmaxf(red[0], red[1]), fmaxf(red[2], red[3]));
        amax[blockIdx.x] = __float_as_uint(m);
    }
}

// ---------------- fused quantize (8 floats/thread/iter -> uint2) ----------------
__global__ void quant2_kernel(const float* __restrict__ x, long nx8,
                              const float* __restrict__ w, long nw8,
                              const unsigned* __restrict__ amax_bits,
                              unsigned* __restrict__ qx, unsigned* __restrict__ qw,
                              int ga) {
    const float* src; long n8; unsigned* q; int bid, blocks; float a;
    if ((int)blockIdx.x < ga) { src = x; n8 = nx8; q = qx; bid = blockIdx.x; blocks = ga;
                                a = __uint_as_float(amax_bits[0]); }
    else { src = w; n8 = nw8; q = qw; bid = blockIdx.x - ga; blocks = gridDim.x - ga;
           a = __uint_as_float(amax_bits[1]); }
    const float scale = fminf(FP8_MAX_F / fmaxf(a, 1e-12f), FP8_MAX_F);

    const long stride = (long)blocks * blockDim.x;
    for (long i = (long)bid * blockDim.x + threadIdx.x; i < n8; i += stride) {
        f32x4 v0 = *(const f32x4*)(src + i * 8);
        f32x4 v1 = *(const f32x4*)(src + i * 8 + 4);
        float c0 = fminf(fmaxf(v0.x * scale, -FP8_MAX_F), FP8_MAX_F);
        float c1 = fminf(fmaxf(v0.y * scale, -FP8_MAX_F), FP8_MAX_F);
        float c2 = fminf(fmaxf(v0.z * scale, -FP8_MAX_F), FP8_MAX_F);
        float c3 = fminf(fmaxf(v0.w * scale, -FP8_MAX_F), FP8_MAX_F);
        float c4 = fminf(fmaxf(v1.x * scale, -FP8_MAX_F), FP8_MAX_F);
        float c5 = fminf(fmaxf(v1.y * scale, -FP8_MAX_F), FP8_MAX_F);
        float c6 = fminf(fmaxf(v1.z * scale, -FP8_MAX_F), FP8_MAX_F);
        float c7 = fminf(fmaxf(v1.w * scale, -FP8_MAX_F), FP8_MAX_F);
        int r0 = __builtin_amdgcn_cvt_pk_fp8_f32(c0, c1, 0, false);
        r0 = __builtin_amdgcn_cvt_pk_fp8_f32(c2, c3, r0, true);
        int r1 = __builtin_amdgcn_cvt_pk_fp8_f32(c4, c5, 0, false);
        r1 = __builtin_amdgcn_cvt_pk_fp8_f32(c6, c7, r1, true);
        uint2 rr; rr.x = (unsigned)r0; rr.y = (unsigned)r1;
        *(uint2*)(q + i * 2) = rr;
    }
}

// ---------------- fp8 GEMM, 256x256 tile, BK=64, mfma_scale 32x32x64, read-ahead pipeline ----------------
// LDS per slot/side: linear [c=0..3][row=0..255][16B] (conflict-free, verified R4/R6/R7: 0 conflicts).
// Lane (l31, g=l>>5) reads units (row, c=2g) and (row, c=2g+1); unit e8m0 scales (0x7F) make
// mfma_scale numerically == plain fp8 GEMM at the 2x MX rate (R8-verified, absmax 1 ulp).
// Read-ahead pipeline (3 slots, stage 3 tiles deep): slot(t+1) is published at the barrier
// ENTERING tile t (vmcnt(4) there retired S(t+1)), so frags(t+1) are read DURING tile t,
// underneath MFMA(t) which needs no lgkm wait (its frags were read+drained during t-1).
//   BODY(t): STAGE(t+3 -> slot t%3) ; RD_FRAGS(t+1) ; MFMA8(t) ; lgkm0 ; vmcnt(4) ; barrier
// WAR: slot t%3's last reads (frags(t), during t-1) drained by t-1's lgkm0 before its barrier.
// RAW: vmcnt(4) leaves exactly S(t+3) in flight -> S(t+2) retired, published by the barrier.
__global__ __launch_bounds__(512, 1) void gemm_fp8_kernel(
    const unsigned char* __restrict__ Xq,   // [M][K] fp8
    const unsigned char* __restrict__ Wq,   // [N][K] fp8
    const float* __restrict__ bias,         // [N]
    const unsigned* __restrict__ amax_bits, // [0]=x amax, [1]=w amax
    float* __restrict__ out,                // [M][N] f32 (bf16-rounded values)
    int M, int N, int K, int nbn)
{
    __shared__ unsigned char ldsA[3][16384];
    __shared__ unsigned char ldsB[3][16384];

    const int tid  = threadIdx.x;
    const int lane = tid & 63;
    const int wave = tid >> 6;
    const int wm128 = (wave >> 2) * 128;  // 2 M-halves
    const int wn64  = (wave & 3) * 64;    // 4 N-quarters

    const int l31 = lane & 31;
    const int g   = lane >> 5;            // k-group: 0 -> k 0..31, 1 -> k 32..63

    // XCD-aware swizzle (nwg % 8 == 0), bn-fastest for A-panel L2 reuse
    const int cpx = gridDim.x >> 3;
    const int wg  = ((int)blockIdx.x & 7) * cpx + ((int)blockIdx.x >> 3);
    const int bn = wg % nbn;
    const int bm = wg / nbn;
    const int rowStart = bm << 8;
    const int colStart = bn << 8;

    // LDS read offsets: low 16B at c=2g, high 16B at c=2g+1 (+4096)
    const int aoffL = (2 * g) * 4096 + (wm128 + l31) * 16;   // + mt*512
    const int boffL = (2 * g) * 4096 + (wn64  + l31) * 16;   // + nt*512

    // staging source offsets (fully linear; dest = tid*16, wave-uniform base + lane*16)
    const size_t aoffs = (size_t)(rowStart + (tid & 255)) * K + (tid >> 8) * 16;
    const size_t boffs = (size_t)(colStart + (tid & 255)) * K + (tid >> 8) * 16;
    const int tid16 = tid * 16;

    union Frag { i32x8 v; struct { i32x4 lo, hi; } h; };
    f32x16 acc[4][2] = {};

#define STAGE_A(t, sl)                                                                          \
    do {                                                                                        \
        const size_t kk_ = (size_t)(t) * 64;                                                    \
        __builtin_amdgcn_global_load_lds(                                                       \
            (const __attribute__((address_space(1))) void*)(Xq + aoffs + kk_),                  \
            (__attribute__((address_space(3))) void*)(&ldsA[sl][tid16]), 16, 0, 0);             \
        __builtin_amdgcn_global_load_lds(                                                       \
            (const __attribute__((address_space(1))) void*)(Xq + aoffs + 32 + kk_),             \
            (__attribute__((address_space(3))) void*)(&ldsA[sl][8192 + tid16]), 16, 0, 0);      \
    } while (0)

#define STAGE_B(t, sl)                                                                          \
    do {                                                                                        \
        const size_t kk_ = (size_t)(t) * 64;                                                    \
        __builtin_amdgcn_global_load_lds(                                                       \
            (const __attribute__((address_space(1))) void*)(Wq + boffs + kk_),                  \
            (__attribute__((address_space(3))) void*)(&ldsB[sl][tid16]), 16, 0, 0);             \
        __builtin_amdgcn_global_load_lds(                                                       \
            (const __attribute__((address_space(1))) void*)(Wq + boffs + 32 + kk_),             \
            (__attribute__((address_space(3))) void*)(&ldsB[sl][8192 + tid16]), 16, 0, 0);      \
    } while (0)

#define RD_FRAGS(sl, FA, FB)                                                                    \
    do {                                                                                        \
        const unsigned char* rA_ = &ldsA[sl][0];                                                \
        const unsigned char* rB_ = &ldsB[sl][0];                                                \
        _Pragma("unroll")                                                                       \
        for (int mt_ = 0; mt_ < 4; ++mt_) {                                                     \
            FA[mt_].h.lo = *(const i32x4*)(rA_ + aoffL + mt_ * 512);                            \
            FA[mt_].h.hi = *(const i32x4*)(rA_ + aoffL + 4096 + mt_ * 512);                     \
        }                                                                                       \
        _Pragma("unroll")                                                                       \
        for (int nt_ = 0; nt_ < 2; ++nt_) {                                                     \
            FB[nt_].h.lo = *(const i32x4*)(rB_ + boffL + nt_ * 512);                            \
            FB[nt_].h.hi = *(const i32x4*)(rB_ + boffL + 4096 + nt_ * 512);                     \
        }                                                                                       \
    } while (0)

#define MFMA8(FA, FB)                                                                           \
    do {                                                                                        \
        __builtin_amdgcn_s_setprio(1);                                                          \
        _Pragma("unroll")                                                                       \
        for (int mt_ = 0; mt_ < 4; ++mt_)                                                       \
            _Pragma("unroll")                                                                   \
            for (int nt_ = 0; nt_ < 2; ++nt_)                                                   \
                acc[mt_][nt_] = __builtin_amdgcn_mfma_scale_f32_32x32x64_f8f6f4(                \
                    FA[mt_].v, FB[nt_].v, acc[mt_][nt_], 0, 0, 0, SCL1, 0, SCL1);               \
        __builtin_amdgcn_s_setprio(0);                                                          \
    } while (0)

// One K-tile: stage t+3; read frags(t+1) (slot published at the barrier entering this tile);
// MFMA this tile's frags (already in regs, no wait); drain reads; counted vmcnt; publish.
#define BODY(t, sRead, sStage, FA, FB, FA2, FB2)                                                \
    do {                                                                                        \
        if ((t) + 3 < nT) { STAGE_A((t) + 3, sStage); STAGE_B((t) + 3, sStage); }               \
        if ((t) + 1 < nT) RD_FRAGS(sRead, FA2, FB2);                                            \
        __builtin_amdgcn_sched_barrier(0);                                                      \
        MFMA8(FA, FB);                                                                          \
        asm volatile("s_waitcnt lgkmcnt(0)" ::: "memory");                                      \
        if ((t) + 3 < nT) asm volatile("s_waitcnt vmcnt(4)" ::: "memory");                      \
        else              asm volatile("s_waitcnt vmcnt(0)" ::: "memory");                      \
        __builtin_amdgcn_s_barrier();                                                           \
        __builtin_amdgcn_sched_barrier(0);                                                      \
    } while (0)

    // prologue: stage tiles 0,1,2 -> slots 0,1,2; publish 0 AND 1 (vmcnt(4): S(2) in flight);
    // preload frags(0) and drain (so BODY(0) can restage slot 0 and MFMA immediately).
    STAGE_A(0, 0); STAGE_B(0, 0);
    STAGE_A(1, 1); STAGE_B(1, 1);
    STAGE_A(2, 2); STAGE_B(2, 2);
    asm volatile("s_waitcnt vmcnt(4)" ::: "memory");
    __builtin_amdgcn_s_barrier();
    __builtin_amdgcn_sched_barrier(0);

    Frag faA[4], fbA[2], faB[4], fbB[2];
    RD_FRAGS(0, faA, fbA);
    asm volatile("s_waitcnt lgkmcnt(0)" ::: "memory");
    __builtin_amdgcn_sched_barrier(0);

    const int nT = K >> 6;   // 16
    int s = 0;
#pragma unroll 1
    for (int t = 0; t < nT; t += 2) {
        const int s1 = (s + 1 >= 3) ? s - 2 : s + 1;
        const int s2 = (s + 2 >= 3) ? s - 1 : s + 2;
        BODY(t,     s1, s,  faA, fbA, faB, fbB);   // tile t (slot s): read t+1, stage t+3 -> s
        BODY(t + 1, s2, s1, faB, fbB, faA, fbA);   // tile t+1 (slot s1): read t+2, stage t+4 -> s1
        s = s2;
    }
#undef BODY
#undef MFMA8
#undef RD_FRAGS
#undef STAGE_A
#undef STAGE_B

    // ---- epilogue: dequant scale, bias, bf16 round, f32 store ----
    // 32x32 C/D layout: col = lane&31, row = (r&3) + 8*(r>>2) + 4*(lane>>5)
    const float ax = __uint_as_float(amax_bits[0]);
    const float aw = __uint_as_float(amax_bits[1]);
    const float sx = fminf(FP8_MAX_F / fmaxf(ax, 1e-12f), FP8_MAX_F);
    const float sw = fminf(FP8_MAX_F / fmaxf(aw, 1e-12f), FP8_MAX_F);
    const float sc = (1.0f / sx) * (1.0f / sw);

#pragma unroll
    for (int nt = 0; nt < 2; ++nt) {
        const int col = colStart + wn64 + nt * 32 + l31;
        const float bv = bias[col];
#pragma unroll
        for (int mt = 0; mt < 4; ++mt) {
#pragma unroll
            for (int r = 0; r < 16; ++r) {
                const int row = rowStart + wm128 + mt * 32 + (r & 3) + 8 * (r >> 2) + 4 * g;
                float tt = acc[mt][nt][r] * sc;   // mul...
                tt = tt + bv;                     // ...then add (match jnp op order)
                out[(size_t)row * N + col] = __bfloat162float(__float2bfloat16(tt));
            }
        }
    }
}

extern "C" void kernel_launch(void* const* d_in, const int* in_sizes, int n_in,
                              void* d_out, int out_size, void* d_ws, size_t ws_size,
                              hipStream_t stream) {
    const float* input  = (const float*)d_in[0];
    const float* weight = (const float*)d_in[1];
    const float* bias   = (const float*)d_in[2];
    float* out = (float*)d_out;

    const int K = 1024;                       // weight [N,K] = [1024,1024]
    const int N = in_sizes[2];                // 1024 (bias length)
    const long nX = in_sizes[0];              // 33554432
    const long nW = (long)N * K;              // 1048576
    const int M = (int)(nX / K);              // 32768

    const int GA = 1984;                      // input blocks (of 2048 total)
    const int GW = 64;                        // weight blocks

    unsigned char* ws = (unsigned char*)d_ws;
    unsigned* amax = (unsigned*)ws;           // [0]=x amax bits, [1]=w amax bits
    unsigned char* Xq = ws + 256;
    unsigned char* Wq = Xq + (size_t)M * K;
    float* px = (float*)(Wq + (size_t)N * K); // 1984 partials
    float* pw = px + GA;                      // 64 partials

    // stage 1: per-block partials (plain stores, no atomic contention)
    amax2_kernel<<<GA + GW, 256, 0, stream>>>(input, nX, weight, nW, px, pw, GA);
    // stage 2: 2 blocks reduce partials -> amax bits (deterministic)
    amax_final_kernel<<<2, 256, 0, stream>>>(px, GA, pw, GW, amax);

    quant2_kernel<<<2048, 256, 0, stream>>>(input, nX / 8, weight, nW / 8, amax,
                                            (unsigned*)Xq, (unsigned*)Wq, GA);

    const int nbn = N / 256;                  // 4
    const int nwg = (M / 256) * nbn;          // 512
    gemm_fp8_kernel<<<dim3(nwg), dim3(512), 0, stream>>>(Xq, Wq, bias, amax, out, M, N, K, nbn);
}

// Round 10
// 153.742 us; speedup vs baseline: 1.1746x; 1.1746x over previous
//
#include <hip/hip_runtime.h>
#include <hip/hip_bf16.h>

typedef float f32x4 __attribute__((ext_vector_type(4)));
typedef float f32x16 __attribute__((ext_vector_type(16)));
typedef int   i32x4  __attribute__((ext_vector_type(4)));
typedef int   i32x8  __attribute__((ext_vector_type(8)));

#define FP8_MAX_F 448.0f
#define SCL1 0x7F7F7F7Fu   /* e8m0 exponent 127 -> scale 1.0, all 4 bytes */

__device__ __forceinline__ float wave_max(float m) {
#pragma unroll
    for (int off = 32; off > 0; off >>= 1)
        m = fmaxf(m, __shfl_xor(m, off));
    return m;
}

// ---------------- stage 1: per-block abs-max partials (no atomics) ----------------
__global__ void amax2_kernel(const float* __restrict__ x, long nx,
                             const float* __restrict__ w, long nw,
                             float* __restrict__ px, float* __restrict__ pw,
                             int ga) {
    __shared__ float red[4];
    const float* src; long n; float* dst; int bid, blocks;
    if ((int)blockIdx.x < ga) { src = x; n = nx; dst = px; bid = blockIdx.x; blocks = ga; }
    else { src = w; n = nw; dst = pw; bid = blockIdx.x - ga; blocks = gridDim.x - ga; }

    const long stride = (long)blocks * blockDim.x * 16;
    long i = ((long)bid * blockDim.x + threadIdx.x) * 16;
    float m = 0.0f;
    for (; i < n; i += stride) {
        f32x4 v0 = *(const f32x4*)(src + i);
        f32x4 v1 = *(const f32x4*)(src + i + 4);
        f32x4 v2 = *(const f32x4*)(src + i + 8);
        f32x4 v3 = *(const f32x4*)(src + i + 12);
        float m0 = fmaxf(fmaxf(fabsf(v0.x), fabsf(v0.y)), fmaxf(fabsf(v0.z), fabsf(v0.w)));
        float m1 = fmaxf(fmaxf(fabsf(v1.x), fabsf(v1.y)), fmaxf(fabsf(v1.z), fabsf(v1.w)));
        float m2 = fmaxf(fmaxf(fabsf(v2.x), fabsf(v2.y)), fmaxf(fabsf(v2.z), fabsf(v2.w)));
        float m3 = fmaxf(fmaxf(fabsf(v3.x), fabsf(v3.y)), fmaxf(fabsf(v3.z), fabsf(v3.w)));
        m = fmaxf(m, fmaxf(fmaxf(m0, m1), fmaxf(m2, m3)));
    }
    m = wave_max(m);
    const int wave = threadIdx.x >> 6;
    if ((threadIdx.x & 63) == 0) red[wave] = m;
    __syncthreads();
    if (threadIdx.x == 0)
        dst[bid] = fmaxf(fmaxf(red[0], red[1]), fmaxf(red[2], red[3]));
}

// ---------------- stage 2: reduce partials -> amax bits (block 0 = x, block 1 = w) ----------------
__global__ void amax_final_kernel(const float* __restrict__ px, int npx,
                                  const float* __restrict__ pw, int npw,
                                  unsigned* __restrict__ amax) {
    __shared__ float red[4];
    const float* p; int n;
    if (blockIdx.x == 0) { p = px; n = npx; } else { p = pw; n = npw; }
    float m = 0.0f;
    for (int i = threadIdx.x; i < n; i += blockDim.x) m = fmaxf(m, p[i]);
    m = wave_max(m);
    const int wave = threadIdx.x >> 6;
    if ((threadIdx.x & 63) == 0) red[wave] = m;
    __syncthreads();
    if (threadIdx.x == 0) {
        m = fmaxf(fmaxf(red[0], red[1]), fmaxf(red[2], red[3]));
        amax[blockIdx.x] = __float_as_uint(m);
    }
}

// ---------------- fused quantize (8 floats/thread/iter -> uint2) ----------------
__global__ void quant2_kernel(const float* __restrict__ x, long nx8,
                              const float* __restrict__ w, long nw8,
                              const unsigned* __restrict__ amax_bits,
                              unsigned* __restrict__ qx, unsigned* __restrict__ qw,
                              int ga) {
    const float* src; long n8; unsigned* q; int bid, blocks; float a;
    if ((int)blockIdx.x < ga) { src = x; n8 = nx8; q = qx; bid = blockIdx.x; blocks = ga;
                                a = __uint_as_float(amax_bits[0]); }
    else { src = w; n8 = nw8; q = qw; bid = blockIdx.x - ga; blocks = gridDim.x - ga;
           a = __uint_as_float(amax_bits[1]); }
    const float scale = fminf(FP8_MAX_F / fmaxf(a, 1e-12f), FP8_MAX_F);

    const long stride = (long)blocks * blockDim.x;
    for (long i = (long)bid * blockDim.x + threadIdx.x; i < n8; i += stride) {
        f32x4 v0 = *(const f32x4*)(src + i * 8);
        f32x4 v1 = *(const f32x4*)(src + i * 8 + 4);
        float c0 = fminf(fmaxf(v0.x * scale, -FP8_MAX_F), FP8_MAX_F);
        float c1 = fminf(fmaxf(v0.y * scale, -FP8_MAX_F), FP8_MAX_F);
        float c2 = fminf(fmaxf(v0.z * scale, -FP8_MAX_F), FP8_MAX_F);
        float c3 = fminf(fmaxf(v0.w * scale, -FP8_MAX_F), FP8_MAX_F);
        float c4 = fminf(fmaxf(v1.x * scale, -FP8_MAX_F), FP8_MAX_F);
        float c5 = fminf(fmaxf(v1.y * scale, -FP8_MAX_F), FP8_MAX_F);
        float c6 = fminf(fmaxf(v1.z * scale, -FP8_MAX_F), FP8_MAX_F);
        float c7 = fminf(fmaxf(v1.w * scale, -FP8_MAX_F), FP8_MAX_F);
        int r0 = __builtin_amdgcn_cvt_pk_fp8_f32(c0, c1, 0, false);
        r0 = __builtin_amdgcn_cvt_pk_fp8_f32(c2, c3, r0, true);
        int r1 = __builtin_amdgcn_cvt_pk_fp8_f32(c4, c5, 0, false);
        r1 = __builtin_amdgcn_cvt_pk_fp8_f32(c6, c7, r1, true);
        uint2 rr; rr.x = (unsigned)r0; rr.y = (unsigned)r1;
        *(uint2*)(q + i * 2) = rr;
    }
}

// ---------------- fp8 GEMM, 256x256 tile, BK=64, mfma_scale 32x32x64, 4-slot A-read-ahead ----------------
// LDS per slot/side: linear [c=0..3][row=0..255][16B] (conflict-free, verified R4-R9: 0 conflicts).
// Unit e8m0 scales (0x7F) make mfma_scale numerically == plain fp8 GEMM at 2x rate (R8-verified).
// 4-slot pipeline, stage depth 3, asymmetric read-ahead (register-budgeted after R9's spill):
//   BODY(t): STAGE(t+3 -> slot (t+3)&3 == (t-1)&3)   [slot fully drained >=1 barrier ago]
//            RD_A(slot (t+1)&3)                       [published at barrier(t-1); 8 reads fly under MFMA]
//            lgkm(8) [retires FB(t), read at bottom(t-1); DS retires in-order]
//            MFMA8(FA(t), FB(t))                      [FA(t) read at top(t-1), drained by its lgkm(0)]
//            lgkm(0) [FA(t+1) done - free]; vmcnt(4) [retire S(t+2)]; barrier [publish t+2]
//            RD_B(slot (t+1)&3)                       [4 reads, drained by next body's lgkm(8)]
// Peak VGPR liveness at MFMA: FA 32 + FA2 32 + FB 16 + addr ~20 = ~100 VGPR + 128 AGPR < 256. No spill.
__global__ __launch_bounds__(512, 1) void gemm_fp8_kernel(
    const unsigned char* __restrict__ Xq,   // [M][K] fp8
    const unsigned char* __restrict__ Wq,   // [N][K] fp8
    const float* __restrict__ bias,         // [N]
    const unsigned* __restrict__ amax_bits, // [0]=x amax, [1]=w amax
    float* __restrict__ out,                // [M][N] f32 (bf16-rounded values)
    int M, int N, int K, int nbn)
{
    __shared__ unsigned char ldsA[4][16384];
    __shared__ unsigned char ldsB[4][16384];

    const int tid  = threadIdx.x;
    const int lane = tid & 63;
    const int wave = tid >> 6;
    const int wm128 = (wave >> 2) * 128;  // 2 M-halves
    const int wn64  = (wave & 3) * 64;    // 4 N-quarters

    const int l31 = lane & 31;
    const int g   = lane >> 5;            // k-group: 0 -> k 0..31, 1 -> k 32..63

    // XCD-aware swizzle (nwg % 8 == 0), bn-fastest for A-panel L2 reuse
    const int cpx = gridDim.x >> 3;
    const int wg  = ((int)blockIdx.x & 7) * cpx + ((int)blockIdx.x >> 3);
    const int bn = wg % nbn;
    const int bm = wg / nbn;
    const int rowStart = bm << 8;
    const int colStart = bn << 8;

    // LDS read offsets: low 16B at c=2g, high 16B at c=2g+1 (+4096)
    const int aoffL = (2 * g) * 4096 + (wm128 + l31) * 16;   // + mt*512
    const int boffL = (2 * g) * 4096 + (wn64  + l31) * 16;   // + nt*512

    // staging source offsets (fully linear; dest = tid*16)
    const size_t aoffs = (size_t)(rowStart + (tid & 255)) * K + (tid >> 8) * 16;
    const size_t boffs = (size_t)(colStart + (tid & 255)) * K + (tid >> 8) * 16;
    const int tid16 = tid * 16;

    union Frag { i32x8 v; struct { i32x4 lo, hi; } h; };
    f32x16 acc[4][2] = {};

#define STAGE_A(t, sl)                                                                          \
    do {                                                                                        \
        const size_t kk_ = (size_t)(t) * 64;                                                    \
        __builtin_amdgcn_global_load_lds(                                                       \
            (const __attribute__((address_space(1))) void*)(Xq + aoffs + kk_),                  \
            (__attribute__((address_space(3))) void*)(&ldsA[sl][tid16]), 16, 0, 0);             \
        __builtin_amdgcn_global_load_lds(                                                       \
            (const __attribute__((address_space(1))) void*)(Xq + aoffs + 32 + kk_),             \
            (__attribute__((address_space(3))) void*)(&ldsA[sl][8192 + tid16]), 16, 0, 0);      \
    } while (0)

#define STAGE_B(t, sl)                                                                          \
    do {                                                                                        \
        const size_t kk_ = (size_t)(t) * 64;                                                    \
        __builtin_amdgcn_global_load_lds(                                                       \
            (const __attribute__((address_space(1))) void*)(Wq + boffs + kk_),                  \
            (__attribute__((address_space(3))) void*)(&ldsB[sl][tid16]), 16, 0, 0);             \
        __builtin_amdgcn_global_load_lds(                                                       \
            (const __attribute__((address_space(1))) void*)(Wq + boffs + 32 + kk_),             \
            (__attribute__((address_space(3))) void*)(&ldsB[sl][8192 + tid16]), 16, 0, 0);      \
    } while (0)

#define RD_A(sl, FA)                                                                            \
    do {                                                                                        \
        const unsigned char* rA_ = &ldsA[sl][0];                                                \
        _Pragma("unroll")                                                                       \
        for (int mt_ = 0; mt_ < 4; ++mt_) {                                                     \
            FA[mt_].h.lo = *(const i32x4*)(rA_ + aoffL + mt_ * 512);                            \
            FA[mt_].h.hi = *(const i32x4*)(rA_ + aoffL + 4096 + mt_ * 512);                     \
        }                                                                                       \
    } while (0)

#define RD_B(sl, FB)                                                                            \
    do {                                                                                        \
        const unsigned char* rB_ = &ldsB[sl][0];                                                \
        _Pragma("unroll")                                                                       \
        for (int nt_ = 0; nt_ < 2; ++nt_) {                                                     \
            FB[nt_].h.lo = *(const i32x4*)(rB_ + boffL + nt_ * 512);                            \
            FB[nt_].h.hi = *(const i32x4*)(rB_ + boffL + 4096 + nt_ * 512);                     \
        }                                                                                       \
    } while (0)

#define MFMA8(FA, FB)                                                                           \
    do {                                                                                        \
        __builtin_amdgcn_s_setprio(1);                                                          \
        _Pragma("unroll")                                                                       \
        for (int mt_ = 0; mt_ < 4; ++mt_)                                                       \
            _Pragma("unroll")                                                                   \
            for (int nt_ = 0; nt_ < 2; ++nt_)                                                   \
                acc[mt_][nt_] = __builtin_amdgcn_mfma_scale_f32_32x32x64_f8f6f4(                \
                    FA[mt_].v, FB[nt_].v, acc[mt_][nt_], 0, 0, 0, SCL1, 0, SCL1);               \
        __builtin_amdgcn_s_setprio(0);                                                          \
    } while (0)

#define BODY(t, FAc, FBc, FAn, FBn)                                                             \
    do {                                                                                        \
        const int sStage_ = ((t) + 3) & 3;                                                      \
        const int sNext_  = ((t) + 1) & 3;                                                      \
        if ((t) + 3 < nT) { STAGE_A((t) + 3, sStage_); STAGE_B((t) + 3, sStage_); }             \
        if ((t) + 1 < nT) {                                                                     \
            RD_A(sNext_, FAn);                                                                  \
            asm volatile("s_waitcnt lgkmcnt(8)" ::: "memory");                                  \
        } else {                                                                                \
            asm volatile("s_waitcnt lgkmcnt(0)" ::: "memory");                                  \
        }                                                                                       \
        __builtin_amdgcn_sched_barrier(0);                                                      \
        MFMA8(FAc, FBc);                                                                        \
        asm volatile("s_waitcnt lgkmcnt(0)" ::: "memory");                                      \
        if ((t) + 3 < nT) asm volatile("s_waitcnt vmcnt(4)" ::: "memory");                      \
        else              asm volatile("s_waitcnt vmcnt(0)" ::: "memory");                      \
        __builtin_amdgcn_s_barrier();                                                           \
        __builtin_amdgcn_sched_barrier(0);                                                      \
        if ((t) + 1 < nT) RD_B(sNext_, FBn);                                                    \
    } while (0)

    // prologue: stage tiles 0,1,2 -> slots 0,1,2; vmcnt(4) retires S0,S1 -> publish 0,1;
    // read frags(0) fully and drain.
    STAGE_A(0, 0); STAGE_B(0, 0);
    STAGE_A(1, 1); STAGE_B(1, 1);
    STAGE_A(2, 2); STAGE_B(2, 2);
    asm volatile("s_waitcnt vmcnt(4)" ::: "memory");
    __builtin_amdgcn_s_barrier();
    __builtin_amdgcn_sched_barrier(0);

    Frag faE[4], fbE[2], faO[4], fbO[2];
    RD_A(0, faE); RD_B(0, fbE);
    asm volatile("s_waitcnt lgkmcnt(0)" ::: "memory");
    __builtin_amdgcn_sched_barrier(0);

    const int nT = K >> 6;   // 16
#pragma unroll 1
    for (int t = 0; t < nT; t += 2) {
        BODY(t,     faE, fbE, faO, fbO);
        BODY(t + 1, faO, fbO, faE, fbE);
    }
#undef BODY
#undef MFMA8
#undef RD_A
#undef RD_B
#undef STAGE_A
#undef STAGE_B

    // ---- epilogue: dequant scale, bias, bf16 round, f32 store ----
    // 32x32 C/D layout: col = lane&31, row = (r&3) + 8*(r>>2) + 4*(lane>>5)
    const float ax = __uint_as_float(amax_bits[0]);
    const float aw = __uint_as_float(amax_bits[1]);
    const float sx = fminf(FP8_MAX_F / fmaxf(ax, 1e-12f), FP8_MAX_F);
    const float sw = fminf(FP8_MAX_F / fmaxf(aw, 1e-12f), FP8_MAX_F);
    const float sc = (1.0f / sx) * (1.0f / sw);

#pragma unroll
    for (int nt = 0; nt < 2; ++nt) {
        const int col = colStart + wn64 + nt * 32 + l31;
        const float bv = bias[col];
#pragma unroll
        for (int mt = 0; mt < 4; ++mt) {
#pragma unroll
            for (int r = 0; r < 16; ++r) {
                const int row = rowStart + wm128 + mt * 32 + (r & 3) + 8 * (r >> 2) + 4 * g;
                float tt = acc[mt][nt][r] * sc;   // mul...
                tt = tt + bv;                     // ...then add (match jnp op order)
                out[(size_t)row * N + col] = __bfloat162float(__float2bfloat16(tt));
            }
        }
    }
}

extern "C" void kernel_launch(void* const* d_in, const int* in_sizes, int n_in,
                              void* d_out, int out_size, void* d_ws, size_t ws_size,
                              hipStream_t stream) {
    const float* input  = (const float*)d_in[0];
    const float* weight = (const float*)d_in[1];
    const float* bias   = (const float*)d_in[2];
    float* out = (float*)d_out;

    const int K = 1024;                       // weight [N,K] = [1024,1024]
    const int N = in_sizes[2];                // 1024 (bias length)
    const long nX = in_sizes[0];              // 33554432
    const long nW = (long)N * K;              // 1048576
    const int M = (int)(nX / K);              // 32768

    const int GA = 1984;                      // input blocks (of 2048 total)
    const int GW = 64;                        // weight blocks

    unsigned char* ws = (unsigned char*)d_ws;
    unsigned* amax = (unsigned*)ws;           // [0]=x amax bits, [1]=w amax bits
    unsigned char* Xq = ws + 256;
    unsigned char* Wq = Xq + (size_t)M * K;
    float* px = (float*)(Wq + (size_t)N * K); // 1984 partials
    float* pw = px + GA;                      // 64 partials

    // stage 1: per-block partials (plain stores, no atomic contention)
    amax2_kernel<<<GA + GW, 256, 0, stream>>>(input, nX, weight, nW, px, pw, GA);
    // stage 2: 2 blocks reduce partials -> amax bits (deterministic)
    amax_final_kernel<<<2, 256, 0, stream>>>(px, GA, pw, GW, amax);

    quant2_kernel<<<2048, 256, 0, stream>>>(input, nX / 8, weight, nW / 8, amax,
                                            (unsigned*)Xq, (unsigned*)Wq, GA);

    const int nbn = N / 256;                  // 4
    const int nwg = (M / 256) * nbn;          // 512
    gemm_fp8_kernel<<<dim3(nwg), dim3(512), 0, stream>>>(Xq, Wq, bias, amax, out, M, N, K, nbn);
}